// Round 5
// baseline (195.889 us; speedup 1.0000x reference)
//
#include <hip/hip_runtime.h>
#include <hip/hip_bf16.h>
#include <math.h>

#define N_NODES 50000
#define M_NEIGH 16
#define HID     64
#define BATCH   4

#define SEG_LEN   25000   // source-space segment (2 segments)
#define BLK_PER_P 256     // blocks per partition (grid = 2048 ~= resident capacity)
#define KCHUNK    7       // 32-node chunks per block: 256*7=1792 >= 1563

typedef float fvec4 __attribute__((ext_vector_type(4)));

// R5: spatial partitioning (batch x H-half -> 8 XCD partitions, 6.4 MB slab)
// + TEMPORAL partitioning of the gather source: each block processes source
// segment [0,25000) for all its K chunks first, then [25000,50000], holding
// accumulators in registers. Grid = 2048 blocks == resident capacity
// (8 blocks/CU at <=64 VGPR), so all blocks run phase-aligned and the
// instantaneous per-XCD working set is ~3.2 MB < 4 MB L2.
// Pad rows (r == 50000) are folded into segment 1 via clamp + select-0.
__global__ __launch_bounds__(256) void pool_max_kernel(
    const fvec4* __restrict__ x,      // [B, N, 16] fvec4
    const int*   __restrict__ index,  // [N, 16]
    fvec4*       __restrict__ out)    // [B, N, 16] fvec4
{
    const int p     = blockIdx.x & 7;          // XCD partition id
    const int batch = p & 3;
    const int half  = p >> 2;                  // which 32-float half of H
    const int blk   = blockIdx.x >> 3;         // 0..255 within partition
    const int wave  = threadIdx.x >> 6;
    const int lane  = threadIdx.x & 63;
    const int q8    = lane & 7;                // quad within half-row
    const int nic   = wave * 8 + (lane >> 3);  // node-in-chunk 0..31

    const fvec4* xb = x + (size_t)batch * N_NODES * (HID / 4) + half * 8;

    fvec4 acc[KCHUNK];
#pragma unroll
    for (int k = 0; k < KCHUNK; ++k)
        acc[k] = (fvec4){-INFINITY, -INFINITY, -INFINITY, -INFINITY};

#pragma unroll
    for (int seg = 0; seg < 2; ++seg) {
        const int lo = seg * SEG_LEN;
        const int hi = lo + SEG_LEN + seg;     // seg1 upper bound includes pad id 50000
        for (int k = 0; k < KCHUNK; ++k) {
            const int n = (blk * KCHUNK + k) * 32 + nic;
            if (n < N_NODES) {
                const int4* ip = (const int4*)(index + (size_t)n * M_NEIGH);
#pragma unroll
                for (int mm = 0; mm < 4; ++mm) {
                    const int4 r4 = ip[mm];
                    const int rr[4] = {r4.x, r4.y, r4.z, r4.w};
#pragma unroll
                    for (int j = 0; j < 4; ++j) {
                        const int r = rr[j];
                        if (r >= lo && r < hi) {
                            const int rc = r < N_NODES ? r : 0;   // clamp pad
                            fvec4 v = xb[(size_t)rc * (HID / 4) + q8];
                            if (r >= N_NODES) v = (fvec4){0.f, 0.f, 0.f, 0.f};
                            acc[k].x = fmaxf(acc[k].x, v.x);
                            acc[k].y = fmaxf(acc[k].y, v.y);
                            acc[k].z = fmaxf(acc[k].z, v.z);
                            acc[k].w = fmaxf(acc[k].w, v.w);
                        }
                    }
                }
            }
        }
    }

#pragma unroll
    for (int k = 0; k < KCHUNK; ++k) {
        const int n = (blk * KCHUNK + k) * 32 + nic;
        if (n < N_NODES) {
            __builtin_nontemporal_store(acc[k],
                &out[((size_t)batch * N_NODES + n) * (HID / 4) + half * 8 + q8]);
        }
    }
}

extern "C" void kernel_launch(void* const* d_in, const int* in_sizes, int n_in,
                              void* d_out, int out_size, void* d_ws, size_t ws_size,
                              hipStream_t stream) {
    const fvec4* x   = (const fvec4*)d_in[0];
    const int*   idx = (const int*)d_in[1];
    fvec4*       out = (fvec4*)d_out;

    pool_max_kernel<<<BLK_PER_P * 8, 256, 0, stream>>>(x, idx, out);
}